// Round 4
// baseline (214.994 us; speedup 1.0000x reference)
//
#include <hip/hip_runtime.h>
#include <hip/hip_bf16.h>

typedef float  f32x2  __attribute__((ext_vector_type(2)));
typedef float  f32x4  __attribute__((ext_vector_type(4)));
typedef float  f32x16 __attribute__((ext_vector_type(16)));
typedef __bf16 bf16x8 __attribute__((ext_vector_type(8)));

#define MFMA16(A,B,C) __builtin_amdgcn_mfma_f32_16x16x32_bf16((A),(B),(C),0,0,0)
#define MFMA32(A,B,C) __builtin_amdgcn_mfma_f32_32x32x16_bf16((A),(B),(C),0,0,0)
#define EXP2(x) __builtin_amdgcn_exp2f(x)
#define LOG2(x) __builtin_amdgcn_logf(x)

static constexpr int Tn = 2048, Bn = 2, En = 1024, Hn = 16, Dn = 64;
// Q is pre-scaled by (1/sqrt(D)) * log2(e): all score math is in log2 domain.
static constexpr float kQScale = 0.125f * 1.4426950408889634f;

static __device__ __forceinline__ unsigned pack2(float a, float b) {
  union { __bf16 h[2]; unsigned u; } un;
  un.h[0] = (__bf16)a; un.h[1] = (__bf16)b;
  return un.u;
}

// async global->LDS, 16B per lane; LDS dest is wave-uniform base + lane*16
static __device__ __forceinline__ void gload_lds16(const void* g, void* l) {
  __builtin_amdgcn_global_load_lds(
      (const __attribute__((address_space(1))) void*)g,
      (__attribute__((address_space(3))) void*)l, 16, 0, 0);
}

// ---------------------------------------------------------------------------
// Kernel 0: fp32 -> bf16 convert of Q/K/V inputs and both weight matrices.
// 2M granules of 8 elems; grid 8192 x 256 covers exactly.
// ---------------------------------------------------------------------------
__global__ __launch_bounds__(256)
void k_cvt(const float* __restrict__ q, const float* __restrict__ k,
           const float* __restrict__ v, const float* __restrict__ w3,
           const float* __restrict__ wo,
           __bf16* __restrict__ qb, __bf16* __restrict__ kb,
           __bf16* __restrict__ vb, __bf16* __restrict__ w3b,
           __bf16* __restrict__ wob)
{
  const size_t g = (size_t)blockIdx.x * 256 + threadIdx.x;  // granule id
  const float* src;
  __bf16* dst;
  size_t off;
  if (g < 524288)        { src = q;  dst = qb;  off = g; }
  else if (g < 1048576)  { src = k;  dst = kb;  off = g - 524288; }
  else if (g < 1572864)  { src = v;  dst = vb;  off = g - 1048576; }
  else if (g < 1966080)  { src = w3; dst = w3b; off = g - 1572864; }
  else                   { src = wo; dst = wob; off = g - 1966080; }
  const float* p = src + off * 8;
  f32x4 a = *reinterpret_cast<const f32x4*>(p);
  f32x4 b = *reinterpret_cast<const f32x4*>(p + 4);
  bf16x8 o;
  #pragma unroll
  for (int e = 0; e < 4; ++e) { o[e] = (__bf16)a[e]; o[e + 4] = (__bf16)b[e]; }
  *reinterpret_cast<bf16x8*>(dst + off * 8) = o;
}

// ---------------------------------------------------------------------------
// Kernel 1: fused QKV in-projection, bf16 inputs, global_load_lds staging.
// LDS layout: granule-major [4 k-granules][128 rows] x 16B -> frag ds_read_b128
// is 16-lane contiguous (conflict-free); gll dest linear in lane order.
// ---------------------------------------------------------------------------
__global__ __launch_bounds__(256)
void k_qkv(const __bf16* __restrict__ Xq, const __bf16* __restrict__ Xk,
           const __bf16* __restrict__ Xv, const __bf16* __restrict__ W,
           const float* __restrict__ bias,
           __bf16* __restrict__ q_ws, __bf16* __restrict__ k_ws,
           __bf16* __restrict__ v_ws)
{
  __shared__ __align__(16) char a_lds[8192];
  __shared__ __align__(16) char b_lds[8192];
  const int tid = threadIdx.x;
  const int lane = tid & 63, w = tid >> 6;
  const int wr = w >> 1, wc = w & 1;
  const int ag = lane >> 4, lr = lane & 15;
  const int mBase = blockIdx.x * 128;
  const int oBase = blockIdx.y * 128;
  const int which = blockIdx.y >> 3;
  const __bf16* X  = (which == 0) ? Xq : ((which == 1) ? Xk : Xv);
  const __bf16* Wt = W + (size_t)oBase * En;
  __bf16* dst = (which == 0) ? q_ws : ((which == 1) ? k_ws : v_ws);
  const float oscale = (which == 0) ? kQScale : 1.0f;

  // wave-static staging assignments: gi = w*2 + j -> (granule g, row-half h)
  const int g0 = w >> 1, h0 = w & 1;            // gi0 = 2w   -> g=w>>... 
  // gi = 2w+j: g = (2w+j)>>1, h = (2w+j)&1  => j=0: g=w, h=0; j=1: g=w, h=1
  const int gA = w;                             // each wave owns granule w
  char* laA0 = a_lds + gA * 2048;               // rows 0..63
  char* laA1 = a_lds + gA * 2048 + 1024;        // rows 64..127
  char* lbA0 = b_lds + gA * 2048;
  char* lbA1 = b_lds + gA * 2048 + 1024;
  const __bf16* pa0 = X  + (size_t)(mBase + lane) * En + gA * 8;
  const __bf16* pa1 = X  + (size_t)(mBase + 64 + lane) * En + gA * 8;
  const __bf16* pb0 = Wt + (size_t)(lane) * En + gA * 8;
  const __bf16* pb1 = Wt + (size_t)(64 + lane) * En + gA * 8;
  (void)g0; (void)h0;

  f32x4 acc[4][4];
  #pragma unroll
  for (int i = 0; i < 4; ++i)
    #pragma unroll
    for (int j = 0; j < 4; ++j) { f32x4 z = {0.f, 0.f, 0.f, 0.f}; acc[i][j] = z; }

  for (int kk = 0; kk < En; kk += 32) {
    __syncthreads();
    gload_lds16(pa0 + kk, laA0);
    gload_lds16(pa1 + kk, laA1);
    gload_lds16(pb0 + kk, lbA0);
    gload_lds16(pb1 + kk, lbA1);
    __syncthreads();
    bf16x8 af[4], bfr[4];
    #pragma unroll
    for (int mb = 0; mb < 4; ++mb)
      af[mb] = *(const bf16x8*)(a_lds + ag * 2048 + (wr * 64 + mb * 16 + lr) * 16);
    #pragma unroll
    for (int nb = 0; nb < 4; ++nb)
      bfr[nb] = *(const bf16x8*)(b_lds + ag * 2048 + (wc * 64 + nb * 16 + lr) * 16);
    #pragma unroll
    for (int mb = 0; mb < 4; ++mb)
      #pragma unroll
      for (int nb = 0; nb < 4; ++nb)
        acc[mb][nb] = MFMA16(af[mb], bfr[nb], acc[mb][nb]);
  }

  #pragma unroll
  for (int nb = 0; nb < 4; ++nb) {
    int oG = oBase + wc * 64 + nb * 16 + lr;
    float bv = bias[oG];
    int oS = oG & (En - 1);
    int h = oS >> 6, d = oS & 63;
    #pragma unroll
    for (int mb = 0; mb < 4; ++mb)
      #pragma unroll
      for (int r = 0; r < 4; ++r) {
        int i = mBase + wr * 64 + mb * 16 + ag * 4 + r;
        int t = i >> 1, b2 = i & 1;
        dst[(((size_t)(b2 * Hn + h)) * Tn + t) * Dn + d] =
            (__bf16)((acc[mb][nb][r] + bv) * oscale);
      }
  }
}

// ---------------------------------------------------------------------------
// Kernel 1b: V [bh, T, D] -> V^T [bh, D, T]  (bf16), LDS tile transpose.
// ---------------------------------------------------------------------------
__global__ __launch_bounds__(256)
void k_transpose_v(const __bf16* __restrict__ v_ws, __bf16* __restrict__ vt_ws)
{
  __shared__ __bf16 tile[64][72];
  const int bh = blockIdx.x >> 5;
  const int tt = blockIdx.x & 31;
  const int tid = threadIdx.x;
  const __bf16* src = v_ws + ((size_t)bh * Tn + tt * 64) * Dn;
  #pragma unroll
  for (int it = 0; it < 2; ++it) {
    int gi = tid + it * 256;
    int row = gi >> 3, gg = gi & 7;
    *reinterpret_cast<bf16x8*>(&tile[row][gg * 8]) =
        *reinterpret_cast<const bf16x8*>(src + row * Dn + gg * 8);
  }
  __syncthreads();
  __bf16* dst = vt_ws + (size_t)bh * Dn * Tn + tt * 64;
  #pragma unroll
  for (int it = 0; it < 2; ++it) {
    int gi = tid + it * 256;
    int drow = gi >> 3, tg = gi & 7;
    bf16x8 vv;
    #pragma unroll
    for (int e = 0; e < 8; ++e) vv[e] = tile[tg * 8 + e][drow];
    *reinterpret_cast<bf16x8*>(dst + (size_t)drow * Tn + tg * 8) = vv;
  }
}

// ---------------------------------------------------------------------------
// Kernel 2: flash attention, swapped-operand 32x32 MFMA structure (log2 dom.)
// ---------------------------------------------------------------------------
__global__ __launch_bounds__(256, 2)
void k_flash(const __bf16* __restrict__ q_ws, const __bf16* __restrict__ k_ws,
             const __bf16* __restrict__ vt_ws, __bf16* __restrict__ ctx,
             float* __restrict__ stats)
{
  __shared__ __align__(16) char k_sm[8192];   // [64 s][64 d], 128B rows, swizzled
  __shared__ __align__(16) char v_sm[8192];   // [64 d][64 s], 128B rows, swizzled
  __shared__ __align__(16) float es_sm[4][32];

  const int tid = threadIdx.x;
  const int lane = tid & 63, w = tid >> 6;
  const int tl = lane & 31, hi = lane >> 5;
  const int bh = blockIdx.x >> 4;
  const int qt = blockIdx.x & 15;
  const int t0w = qt * 128 + w * 32;

  const __bf16* kbase  = k_ws + (size_t)bh * Tn * Dn;
  const __bf16* vtbase = vt_ws + (size_t)bh * Dn * Tn;

  bf16x8 qf[4];
  {
    const __bf16* qrow = q_ws + ((size_t)bh * Tn + t0w + tl) * Dn + hi * 8;
    #pragma unroll
    for (int c = 0; c < 4; ++c)
      qf[c] = *reinterpret_cast<const bf16x8*>(qrow + c * 16);
  }

  f32x16 accO0, accO1;
  #pragma unroll
  for (int i = 0; i < 16; ++i) { accO0[i] = 0.f; accO1[i] = 0.f; }
  float m_run = -INFINITY, l_run = 0.f;

  const int r0 = tid >> 3, s0 = tid & 7;
  const int ldso = ((s0 ^ (r0 & 7)) << 4);
  const int ko0 = r0 * 128 + ldso, ko1 = ko0 + 32 * 128;

  bf16x8 rk0 = *(const bf16x8*)(kbase + r0 * 64 + s0 * 8);
  bf16x8 rk1 = *(const bf16x8*)(kbase + (r0 + 32) * 64 + s0 * 8);
  bf16x8 rv0 = *(const bf16x8*)(vtbase + (size_t)r0 * Tn + s0 * 8);
  bf16x8 rv1 = *(const bf16x8*)(vtbase + (size_t)(r0 + 32) * Tn + s0 * 8);

  for (int st = 0; st < 32; ++st) {
    __syncthreads();
    *(bf16x8*)(k_sm + ko0) = rk0;
    *(bf16x8*)(k_sm + ko1) = rk1;
    *(bf16x8*)(v_sm + ko0) = rv0;
    *(bf16x8*)(v_sm + ko1) = rv1;
    __syncthreads();
    if (st + 1 < 32) {
      const __bf16* kn = kbase + (size_t)(st + 1) * 64 * Dn;
      const __bf16* vn = vtbase + (st + 1) * 64;
      rk0 = *(const bf16x8*)(kn + r0 * 64 + s0 * 8);
      rk1 = *(const bf16x8*)(kn + (r0 + 32) * 64 + s0 * 8);
      rv0 = *(const bf16x8*)(vn + (size_t)r0 * Tn + s0 * 8);
      rv1 = *(const bf16x8*)(vn + (size_t)(r0 + 32) * Tn + s0 * 8);
    }

    f32x16 sc0, sc1;
    #pragma unroll
    for (int i = 0; i < 16; ++i) { sc0[i] = 0.f; sc1[i] = 0.f; }
    const char* kr0 = k_sm + tl * 128;
    const char* kr1 = k_sm + (32 + tl) * 128;
    #pragma unroll
    for (int c = 0; c < 4; ++c) {
      const int off = (((2 * c + hi) ^ (tl & 7)) << 4);
      sc0 = MFMA32(*(const bf16x8*)(kr0 + off), qf[c], sc0);
      sc1 = MFMA32(*(const bf16x8*)(kr1 + off), qf[c], sc1);
    }

    float mx[8];
    #pragma unroll
    for (int i = 0; i < 8; ++i)
      mx[i] = fmaxf(fmaxf(sc0[i], sc0[i + 8]), fmaxf(sc1[i], sc1[i + 8]));
    float tm = fmaxf(fmaxf(fmaxf(mx[0], mx[1]), fmaxf(mx[2], mx[3])),
                     fmaxf(fmaxf(mx[4], mx[5]), fmaxf(mx[6], mx[7])));
    tm = fmaxf(tm, __shfl_xor(tm, 32, 64));
    const float mn = fmaxf(m_run, tm);
    const float es = EXP2(m_run - mn);
    m_run = mn;
    #pragma unroll
    for (int i = 0; i < 16; ++i) {
      sc0[i] = EXP2(sc0[i] - mn);
      sc1[i] = EXP2(sc1[i] - mn);
    }
    float p0s = 0.f, p1s = 0.f, p2s = 0.f, p3s = 0.f;
    #pragma unroll
    for (int i = 0; i < 16; i += 4) {
      p0s += sc0[i]     + sc1[i];
      p1s += sc0[i + 1] + sc1[i + 1];
      p2s += sc0[i + 2] + sc1[i + 2];
      p3s += sc0[i + 3] + sc1[i + 3];
    }
    float rs = (p0s + p1s) + (p2s + p3s);
    rs += __shfl_xor(rs, 32, 64);
    l_run = l_run * es + rs;

    es_sm[w][tl] = es;
    f32x4 esr[4];
    #pragma unroll
    for (int q = 0; q < 4; ++q)
      esr[q] = *(const f32x4*)&es_sm[w][8 * q + 4 * hi];
    #pragma unroll
    for (int q = 0; q < 4; ++q)
      #pragma unroll
      for (int rr = 0; rr < 4; ++rr) {
        accO0[q * 4 + rr] *= esr[q][rr];
        accO1[q * 4 + rr] *= esr[q][rr];
      }

    unsigned wA0[4], wB0[4], wA1[4], wB1[4];
    #pragma unroll
    for (int g = 0; g < 4; ++g) {
      wA0[g] = pack2(sc0[4 * g],     sc0[4 * g + 1]);
      wB0[g] = pack2(sc0[4 * g + 2], sc0[4 * g + 3]);
      wA1[g] = pack2(sc1[4 * g],     sc1[4 * g + 1]);
      wB1[g] = pack2(sc1[4 * g + 2], sc1[4 * g + 3]);
    }
    bf16x8 pa[2][2];
    #pragma unroll
    for (int sb = 0; sb < 2; ++sb) {
      const unsigned* WA = sb ? wA1 : wA0;
      const unsigned* WB = sb ? wB1 : wB0;
      #pragma unroll
      for (int c = 0; c < 2; ++c) {
        unsigned a0 = WA[2 * c], a1 = WA[2 * c + 1];
        unsigned b0 = WB[2 * c], b1 = WB[2 * c + 1];
        unsigned xa0 = __shfl_xor(a0, 32, 64);
        unsigned xa1 = __shfl_xor(a1, 32, 64);
        unsigned xb0 = __shfl_xor(b0, 32, 64);
        unsigned xb1 = __shfl_xor(b1, 32, 64);
        union { unsigned u[4]; bf16x8 v; } uu;
        uu.u[0] = hi ? xa1 : a0;
        uu.u[1] = hi ? xb1 : b0;
        uu.u[2] = hi ? a1 : xa0;
        uu.u[3] = hi ? b1 : xb0;
        pa[sb][c] = uu.v;
      }
    }

    const char* vr0 = v_sm + tl * 128;
    const char* vr1 = v_sm + (32 + tl) * 128;
    #pragma unroll
    for (int sb = 0; sb < 2; ++sb)
      #pragma unroll
      for (int c = 0; c < 2; ++c) {
        const int off = (((sb * 4 + c * 2 + hi) ^ (tl & 7)) << 4);
        accO0 = MFMA32(pa[sb][c], *(const bf16x8*)(vr0 + off), accO0);
        accO1 = MFMA32(pa[sb][c], *(const bf16x8*)(vr1 + off), accO1);
      }
  }

  const float linv = 1.0f / l_run;
  es_sm[w][tl] = linv;
  f32x4 lr[4];
  #pragma unroll
  for (int q = 0; q < 4; ++q)
    lr[q] = *(const f32x4*)&es_sm[w][8 * q + 4 * hi];
  const int b2 = bh >> 4, h = bh & 15;
  #pragma unroll
  for (int q = 0; q < 4; ++q)
    #pragma unroll
    for (int rr = 0; rr < 4; ++rr) {
      const int t = t0w + 8 * q + 4 * hi + rr;
      __bf16* cp = ctx + ((size_t)t * Bn + b2) * En + h * 64 + tl;
      cp[0]  = (__bf16)(accO0[q * 4 + rr] * lr[q][rr]);
      cp[32] = (__bf16)(accO1[q * 4 + rr] * lr[q][rr]);
    }
  if (hi == 0) {
    const int t = t0w + tl;
    f32x2 stv; stv[0] = m_run; stv[1] = l_run;
    *reinterpret_cast<f32x2*>(&stats[((size_t)bh * Tn + t) * 2]) = stv;
  }
}

// ---------------------------------------------------------------------------
// Kernel 3: avg attention weights (recompute QK^T; log2-domain stats).
// ---------------------------------------------------------------------------
__global__ __launch_bounds__(256)
void k_avgw(const __bf16* __restrict__ q_ws, const __bf16* __restrict__ k_ws,
            const float* __restrict__ stats, float* __restrict__ avg_out)
{
  __shared__ __align__(16) char q_sm[8192];
  __shared__ __align__(16) char k_sm[8192];
  __shared__ __align__(16) float adj_sm[16][64];

  const int tid = threadIdx.x;
  const int lane = tid & 63, w = tid >> 6;
  const int tl = lane & 31, hi = lane >> 5;
  const int b2 = blockIdx.x >> 10;
  const int tt = (blockIdx.x >> 5) & 31;
  const int ss = blockIdx.x & 31;
  const int thalf = (w >> 1) * 32, shalf = (w & 1) * 32;

  #pragma unroll
  for (int it = 0; it < 4; ++it) {
    int idx = tid + it * 256;
    int h = idx >> 6, trow = idx & 63;
    f32x2 sv = *(const f32x2*)&stats[(((size_t)(b2 * Hn + h)) * Tn + tt * 64 + trow) * 2];
    adj_sm[h][trow] = sv[0] + LOG2(16.0f * sv[1]);
  }

  const size_t hstride = (size_t)Tn * Dn;
  const __bf16* qb = q_ws + ((size_t)(b2 * Hn) * Tn + tt * 64) * Dn;
  const __bf16* kb = k_ws + ((size_t)(b2 * Hn) * Tn + ss * 64) * Dn;

  const int r0 = tid >> 3, s0 = tid & 7;
  const int ldso = ((s0 ^ (r0 & 7)) << 4);
  const int ko0 = r0 * 128 + ldso, ko1 = ko0 + 32 * 128;

  bf16x8 rq0 = *(const bf16x8*)(qb + r0 * 64 + s0 * 8);
  bf16x8 rq1 = *(const bf16x8*)(qb + (r0 + 32) * 64 + s0 * 8);
  bf16x8 rk0 = *(const bf16x8*)(kb + r0 * 64 + s0 * 8);
  bf16x8 rk1 = *(const bf16x8*)(kb + (r0 + 32) * 64 + s0 * 8);

  f32x16 avg;
  #pragma unroll
  for (int i = 0; i < 16; ++i) avg[i] = 0.f;

  const char* qr = q_sm + (thalf + tl) * 128;
  const char* kr = k_sm + (shalf + tl) * 128;

  for (int h = 0; h < Hn; ++h) {
    __syncthreads();
    *(bf16x8*)(q_sm + ko0) = rq0;
    *(bf16x8*)(q_sm + ko1) = rq1;
    *(bf16x8*)(k_sm + ko0) = rk0;
    *(bf16x8*)(k_sm + ko1) = rk1;
    __syncthreads();
    if (h + 1 < Hn) {
      const __bf16* qn = qb + (size_t)(h + 1) * hstride;
      const __bf16* kn = kb + (size_t)(h + 1) * hstride;
      rq0 = *(const bf16x8*)(qn + r0 * 64 + s0 * 8);
      rq1 = *(const bf16x8*)(qn + (r0 + 32) * 64 + s0 * 8);
      rk0 = *(const bf16x8*)(kn + r0 * 64 + s0 * 8);
      rk1 = *(const bf16x8*)(kn + (r0 + 32) * 64 + s0 * 8);
    }

    f32x16 sc;
    #pragma unroll
    for (int i = 0; i < 16; ++i) sc[i] = 0.f;
    #pragma unroll
    for (int c = 0; c < 4; ++c) {
      const int off = (((2 * c + hi) ^ (tl & 7)) << 4);
      sc = MFMA32(*(const bf16x8*)(qr + off), *(const bf16x8*)(kr + off), sc);
    }

    #pragma unroll
    for (int q = 0; q < 4; ++q) {
      f32x4 ad = *(const f32x4*)&adj_sm[h][thalf + 8 * q + 4 * hi];
      #pragma unroll
      for (int r = 0; r < 4; ++r)
        avg[q * 4 + r] += EXP2(sc[q * 4 + r] - ad[r]);
    }
  }

  #pragma unroll
  for (int q = 0; q < 4; ++q)
    #pragma unroll
    for (int r = 0; r < 4; ++r) {
      int t = tt * 64 + thalf + 8 * q + 4 * hi + r;
      int s = ss * 64 + shalf + tl;
      avg_out[((size_t)(b2 * Tn + t)) * Tn + s] = avg[q * 4 + r];
    }
}

// ---------------------------------------------------------------------------
// Kernel 4: out projection, bf16 operands via global_load_lds, fp32 out.
// ---------------------------------------------------------------------------
__global__ __launch_bounds__(256)
void k_outproj(const __bf16* __restrict__ ctx, const __bf16* __restrict__ W,
               const float* __restrict__ bias, float* __restrict__ out)
{
  __shared__ __align__(16) char a_lds[8192];
  __shared__ __align__(16) char b_lds[8192];
  const int tid = threadIdx.x;
  const int lane = tid & 63, w = tid >> 6;
  const int wr = w >> 1, wc = w & 1;
  const int ag = lane >> 4, lr = lane & 15;
  const int mBase = blockIdx.x * 128;
  const int oBase = blockIdx.y * 128;
  const __bf16* Wt = W + (size_t)oBase * En;

  const int gA = w;
  char* laA0 = a_lds + gA * 2048;
  char* laA1 = a_lds + gA * 2048 + 1024;
  char* lbA0 = b_lds + gA * 2048;
  char* lbA1 = b_lds + gA * 2048 + 1024;
  const __bf16* pa0 = ctx + (size_t)(mBase + lane) * En + gA * 8;
  const __bf16* pa1 = ctx + (size_t)(mBase + 64 + lane) * En + gA * 8;
  const __bf16* pb0 = Wt + (size_t)(lane) * En + gA * 8;
  const __bf16* pb1 = Wt + (size_t)(64 + lane) * En + gA * 8;

  f32x4 acc[4][4];
  #pragma unroll
  for (int i = 0; i < 4; ++i)
    #pragma unroll
    for (int j = 0; j < 4; ++j) { f32x4 z = {0.f,0.f,0.f,0.f}; acc[i][j] = z; }

  for (int kk = 0; kk < En; kk += 32) {
    __syncthreads();
    gload_lds16(pa0 + kk, laA0);
    gload_lds16(pa1 + kk, laA1);
    gload_lds16(pb0 + kk, lbA0);
    gload_lds16(pb1 + kk, lbA1);
    __syncthreads();
    bf16x8 af[4], bfr[4];
    #pragma unroll
    for (int mb = 0; mb < 4; ++mb)
      af[mb] = *(const bf16x8*)(a_lds + ag * 2048 + (wr * 64 + mb * 16 + lr) * 16);
    #pragma unroll
    for (int nb = 0; nb < 4; ++nb)
      bfr[nb] = *(const bf16x8*)(b_lds + ag * 2048 + (wc * 64 + nb * 16 + lr) * 16);
    #pragma unroll
    for (int mb = 0; mb < 4; ++mb)
      #pragma unroll
      for (int nb = 0; nb < 4; ++nb)
        acc[mb][nb] = MFMA16(af[mb], bfr[nb], acc[mb][nb]);
  }

  #pragma unroll
  for (int nb = 0; nb < 4; ++nb) {
    int o = oBase + wc * 64 + nb * 16 + lr;
    float bv = bias[o];
    #pragma unroll
    for (int mb = 0; mb < 4; ++mb)
      #pragma unroll
      for (int r = 0; r < 4; ++r) {
        int i = mBase + wr * 64 + mb * 16 + ag * 4 + r;
        out[(size_t)i * En + o] = acc[mb][nb][r] + bv;
      }
  }
}

// ---------------------------------------------------------------------------
extern "C" void kernel_launch(void* const* d_in, const int* in_sizes, int n_in,
                              void* d_out, int out_size, void* d_ws, size_t ws_size,
                              hipStream_t stream)
{
  (void)in_sizes; (void)n_in; (void)out_size; (void)ws_size;
  const float* query = (const float*)d_in[0];
  const float* key   = (const float*)d_in[1];
  const float* value = (const float*)d_in[2];
  const float* in_w  = (const float*)d_in[3];
  const float* in_b  = (const float*)d_in[4];
  const float* out_w = (const float*)d_in[5];
  const float* out_b = (const float*)d_in[6];

  float* attn_out = (float*)d_out;                                 // [T,B,E]
  float* avg_out  = (float*)d_out + (size_t)Tn * Bn * En;          // [B,T,S]

  char* ws = (char*)d_ws;
  const size_t MB = 1u << 20;
  __bf16* q_ws  = (__bf16*)(ws);                    // [B,H,T,D] bf16, 8 MB
  __bf16* k_ws  = (__bf16*)(ws + 8 * MB);           // 8 MB
  __bf16* v_ws  = (__bf16*)(ws + 16 * MB);          // 8 MB
  __bf16* vt_ws = (__bf16*)(ws + 24 * MB);          // 8 MB (aliases xq_bf)
  __bf16* ctx   = (__bf16*)(ws + 32 * MB);          // 8 MB (aliases xk_bf)
  float*  stats = (float*)(ws + 40 * MB);           // 512 KB
  __bf16* xq_bf = vt_ws;                            // dead before transpose
  __bf16* xk_bf = ctx;                              // dead before flash
  __bf16* xv_bf = (__bf16*)(ws + 40 * MB + 512 * 1024);   // 8 MB
  __bf16* w3_bf = (__bf16*)(ws + 48 * MB + 512 * 1024);   // 6 MB
  __bf16* wo_bf = (__bf16*)(ws + 54 * MB + 512 * 1024);   // 2 MB

  k_cvt<<<8192, 256, 0, stream>>>(query, key, value, in_w, out_w,
                                  xq_bf, xk_bf, xv_bf, w3_bf, wo_bf);
  k_qkv<<<dim3(32, 24), 256, 0, stream>>>(xq_bf, xk_bf, xv_bf, w3_bf, in_b,
                                          q_ws, k_ws, v_ws);
  k_transpose_v<<<1024, 256, 0, stream>>>(v_ws, vt_ws);
  k_flash<<<512, 256, 0, stream>>>(q_ws, k_ws, vt_ws, ctx, stats);
  k_avgw<<<2048, 256, 0, stream>>>(q_ws, k_ws, stats, avg_out);
  k_outproj<<<dim3(32, 8), 256, 0, stream>>>(ctx, wo_bf, out_b, attn_out);
}

// Round 5
// 212.476 us; speedup vs baseline: 1.0119x; 1.0119x over previous
//
#include <hip/hip_runtime.h>
#include <hip/hip_bf16.h>

typedef float  f32x2  __attribute__((ext_vector_type(2)));
typedef float  f32x4  __attribute__((ext_vector_type(4)));
typedef float  f32x16 __attribute__((ext_vector_type(16)));
typedef __bf16 bf16x8 __attribute__((ext_vector_type(8)));

#define MFMA16(A,B,C) __builtin_amdgcn_mfma_f32_16x16x32_bf16((A),(B),(C),0,0,0)
#define MFMA32(A,B,C) __builtin_amdgcn_mfma_f32_32x32x16_bf16((A),(B),(C),0,0,0)
#define EXP2(x) __builtin_amdgcn_exp2f(x)
#define LOG2(x) __builtin_amdgcn_logf(x)

static constexpr int Tn = 2048, Bn = 2, En = 1024, Hn = 16, Dn = 64;
// Q is pre-scaled by (1/sqrt(D)) * log2(e): all score math is in log2 domain.
static constexpr float kQScale = 0.125f * 1.4426950408889634f;

static __device__ __forceinline__ unsigned pack2(float a, float b) {
  union { __bf16 h[2]; unsigned u; } un;
  un.h[0] = (__bf16)a; un.h[1] = (__bf16)b;
  return un.u;
}

// async global->LDS, 16B per lane; LDS dest is wave-uniform base + lane*16
static __device__ __forceinline__ void gload_lds16(const void* g, void* l) {
  __builtin_amdgcn_global_load_lds(
      (const __attribute__((address_space(1))) void*)g,
      (__attribute__((address_space(3))) void*)l, 16, 0, 0);
}

// ---------------------------------------------------------------------------
// Kernel 0: fp32 -> bf16 convert of Q/K/V inputs and both weight matrices.
// ---------------------------------------------------------------------------
__global__ __launch_bounds__(256)
void k_cvt(const float* __restrict__ q, const float* __restrict__ k,
           const float* __restrict__ v, const float* __restrict__ w3,
           const float* __restrict__ wo,
           __bf16* __restrict__ qb, __bf16* __restrict__ kb,
           __bf16* __restrict__ vb, __bf16* __restrict__ w3b,
           __bf16* __restrict__ wob)
{
  const size_t g = (size_t)blockIdx.x * 256 + threadIdx.x;  // granule id
  const float* src;
  __bf16* dst;
  size_t off;
  if (g < 524288)        { src = q;  dst = qb;  off = g; }
  else if (g < 1048576)  { src = k;  dst = kb;  off = g - 524288; }
  else if (g < 1572864)  { src = v;  dst = vb;  off = g - 1048576; }
  else if (g < 1966080)  { src = w3; dst = w3b; off = g - 1572864; }
  else                   { src = wo; dst = wob; off = g - 1966080; }
  const float* p = src + off * 8;
  f32x4 a = *reinterpret_cast<const f32x4*>(p);
  f32x4 b = *reinterpret_cast<const f32x4*>(p + 4);
  bf16x8 o;
  #pragma unroll
  for (int e = 0; e < 4; ++e) { o[e] = (__bf16)a[e]; o[e + 4] = (__bf16)b[e]; }
  *reinterpret_cast<bf16x8*>(dst + off * 8) = o;
}

// ---------------------------------------------------------------------------
// Kernel 1: fused QKV in-projection, bf16 inputs, global_load_lds staging.
// ---------------------------------------------------------------------------
__global__ __launch_bounds__(256)
void k_qkv(const __bf16* __restrict__ Xq, const __bf16* __restrict__ Xk,
           const __bf16* __restrict__ Xv, const __bf16* __restrict__ W,
           const float* __restrict__ bias,
           __bf16* __restrict__ q_ws, __bf16* __restrict__ k_ws,
           __bf16* __restrict__ v_ws)
{
  __shared__ __align__(16) char a_lds[8192];
  __shared__ __align__(16) char b_lds[8192];
  const int tid = threadIdx.x;
  const int lane = tid & 63, w = tid >> 6;
  const int wr = w >> 1, wc = w & 1;
  const int ag = lane >> 4, lr = lane & 15;
  const int mBase = blockIdx.x * 128;
  const int oBase = blockIdx.y * 128;
  const int which = blockIdx.y >> 3;
  const __bf16* X  = (which == 0) ? Xq : ((which == 1) ? Xk : Xv);
  const __bf16* Wt = W + (size_t)oBase * En;
  __bf16* dst = (which == 0) ? q_ws : ((which == 1) ? k_ws : v_ws);
  const float oscale = (which == 0) ? kQScale : 1.0f;

  const int gA = w;                             // each wave owns granule w
  char* laA0 = a_lds + gA * 2048;               // rows 0..63
  char* laA1 = a_lds + gA * 2048 + 1024;        // rows 64..127
  char* lbA0 = b_lds + gA * 2048;
  char* lbA1 = b_lds + gA * 2048 + 1024;
  const __bf16* pa0 = X  + (size_t)(mBase + lane) * En + gA * 8;
  const __bf16* pa1 = X  + (size_t)(mBase + 64 + lane) * En + gA * 8;
  const __bf16* pb0 = Wt + (size_t)(lane) * En + gA * 8;
  const __bf16* pb1 = Wt + (size_t)(64 + lane) * En + gA * 8;

  f32x4 acc[4][4];
  #pragma unroll
  for (int i = 0; i < 4; ++i)
    #pragma unroll
    for (int j = 0; j < 4; ++j) { f32x4 z = {0.f, 0.f, 0.f, 0.f}; acc[i][j] = z; }

  for (int kk = 0; kk < En; kk += 32) {
    __syncthreads();
    gload_lds16(pa0 + kk, laA0);
    gload_lds16(pa1 + kk, laA1);
    gload_lds16(pb0 + kk, lbA0);
    gload_lds16(pb1 + kk, lbA1);
    __syncthreads();
    bf16x8 af[4], bfr[4];
    #pragma unroll
    for (int mb = 0; mb < 4; ++mb)
      af[mb] = *(const bf16x8*)(a_lds + ag * 2048 + (wr * 64 + mb * 16 + lr) * 16);
    #pragma unroll
    for (int nb = 0; nb < 4; ++nb)
      bfr[nb] = *(const bf16x8*)(b_lds + ag * 2048 + (wc * 64 + nb * 16 + lr) * 16);
    #pragma unroll
    for (int mb = 0; mb < 4; ++mb)
      #pragma unroll
      for (int nb = 0; nb < 4; ++nb)
        acc[mb][nb] = MFMA16(af[mb], bfr[nb], acc[mb][nb]);
  }

  #pragma unroll
  for (int nb = 0; nb < 4; ++nb) {
    int oG = oBase + wc * 64 + nb * 16 + lr;
    float bv = bias[oG];
    int oS = oG & (En - 1);
    int h = oS >> 6, d = oS & 63;
    #pragma unroll
    for (int mb = 0; mb < 4; ++mb)
      #pragma unroll
      for (int r = 0; r < 4; ++r) {
        int i = mBase + wr * 64 + mb * 16 + ag * 4 + r;
        int t = i >> 1, b2 = i & 1;
        dst[(((size_t)(b2 * Hn + h)) * Tn + t) * Dn + d] =
            (__bf16)((acc[mb][nb][r] + bv) * oscale);
      }
  }
}

// ---------------------------------------------------------------------------
// Kernel 1b: V [bh, T, D] -> V^T [bh, D, T]  (bf16), LDS tile transpose.
// ---------------------------------------------------------------------------
__global__ __launch_bounds__(256)
void k_transpose_v(const __bf16* __restrict__ v_ws, __bf16* __restrict__ vt_ws)
{
  __shared__ __bf16 tile[64][72];
  const int bh = blockIdx.x >> 5;
  const int tt = blockIdx.x & 31;
  const int tid = threadIdx.x;
  const __bf16* src = v_ws + ((size_t)bh * Tn + tt * 64) * Dn;
  #pragma unroll
  for (int it = 0; it < 2; ++it) {
    int gi = tid + it * 256;
    int row = gi >> 3, gg = gi & 7;
    *reinterpret_cast<bf16x8*>(&tile[row][gg * 8]) =
        *reinterpret_cast<const bf16x8*>(src + row * Dn + gg * 8);
  }
  __syncthreads();
  __bf16* dst = vt_ws + (size_t)bh * Dn * Tn + tt * 64;
  #pragma unroll
  for (int it = 0; it < 2; ++it) {
    int gi = tid + it * 256;
    int drow = gi >> 3, tg = gi & 7;
    bf16x8 vv;
    #pragma unroll
    for (int e = 0; e < 8; ++e) vv[e] = tile[tg * 8 + e][drow];
    *reinterpret_cast<bf16x8*>(dst + (size_t)drow * Tn + tg * 8) = vv;
  }
}

// ---------------------------------------------------------------------------
// Kernel 2: flash attention, swapped-operand 32x32 MFMA, log2 domain.
// Double-buffered K/V LDS (1 barrier/iter), defer-max (T13), shfl-based
// rescale broadcast (no es_sm), setprio around MFMA clusters (T5).
// ---------------------------------------------------------------------------
__global__ __launch_bounds__(256, 2)
void k_flash(const __bf16* __restrict__ q_ws, const __bf16* __restrict__ k_ws,
             const __bf16* __restrict__ vt_ws, __bf16* __restrict__ ctx,
             float* __restrict__ stats)
{
  __shared__ __align__(16) char kv_sm[2 * 16384];  // [buf][K 8KB | V 8KB]

  const int tid = threadIdx.x;
  const int lane = tid & 63, w = tid >> 6;
  const int tl = lane & 31, hi = lane >> 5;
  const int bh = blockIdx.x >> 4;
  const int qt = blockIdx.x & 15;
  const int t0w = qt * 128 + w * 32;

  const __bf16* kbase  = k_ws + (size_t)bh * Tn * Dn;
  const __bf16* vtbase = vt_ws + (size_t)bh * Dn * Tn;

  // Q B-frags: lane holds Q[t0w+tl][c*16 + hi*8 + j]
  bf16x8 qf[4];
  {
    const __bf16* qrow = q_ws + ((size_t)bh * Tn + t0w + tl) * Dn + hi * 8;
    #pragma unroll
    for (int c = 0; c < 4; ++c)
      qf[c] = *reinterpret_cast<const bf16x8*>(qrow + c * 16);
  }

  f32x16 accO0, accO1;
  #pragma unroll
  for (int i = 0; i < 16; ++i) { accO0[i] = 0.f; accO1[i] = 0.f; }
  float m_run = -INFINITY, l_run = 0.f;

  // staging: thread owns granule s0 of rows r0 and r0+32 (K and V)
  const int r0 = tid >> 3, s0 = tid & 7;
  const int ldso = ((s0 ^ (r0 & 7)) << 4);
  const int ko0 = r0 * 128 + ldso;              // +4096 => rows 32..63

  bf16x8 rk0 = *(const bf16x8*)(kbase + r0 * 64 + s0 * 8);
  bf16x8 rk1 = *(const bf16x8*)(kbase + (r0 + 32) * 64 + s0 * 8);
  bf16x8 rv0 = *(const bf16x8*)(vtbase + (size_t)r0 * Tn + s0 * 8);
  bf16x8 rv1 = *(const bf16x8*)(vtbase + (size_t)(r0 + 32) * Tn + s0 * 8);
  *(bf16x8*)(kv_sm + ko0) = rk0;
  *(bf16x8*)(kv_sm + ko0 + 4096) = rk1;
  *(bf16x8*)(kv_sm + 8192 + ko0) = rv0;
  *(bf16x8*)(kv_sm + 8192 + ko0 + 4096) = rv1;

  for (int st = 0; st < 32; ++st) {
    __syncthreads();   // cur buf written by all; nxt buf reads (iter st-1) done
    const char* cur = kv_sm + (st & 1) * 16384;
    char* nxt = kv_sm + ((st + 1) & 1) * 16384;
    if (st + 1 < 32) {   // issue next tile's loads; land during compute (T14)
      const __bf16* kn = kbase + (size_t)(st + 1) * 64 * Dn;
      const __bf16* vn = vtbase + (st + 1) * 64;
      rk0 = *(const bf16x8*)(kn + r0 * 64 + s0 * 8);
      rk1 = *(const bf16x8*)(kn + (r0 + 32) * 64 + s0 * 8);
      rv0 = *(const bf16x8*)(vn + (size_t)r0 * Tn + s0 * 8);
      rv1 = *(const bf16x8*)(vn + (size_t)(r0 + 32) * Tn + s0 * 8);
    }

    // QK^T (swapped): sc{0,1}[reg] = S[s = ss*32 + 8*(reg>>2)+4*hi+(reg&3)][tl]
    f32x16 sc0, sc1;
    #pragma unroll
    for (int i = 0; i < 16; ++i) { sc0[i] = 0.f; sc1[i] = 0.f; }
    const char* kr0 = cur + tl * 128;
    const char* kr1 = cur + (32 + tl) * 128;
    __builtin_amdgcn_s_setprio(1);
    #pragma unroll
    for (int c = 0; c < 4; ++c) {
      const int off = (((2 * c + hi) ^ (tl & 7)) << 4);
      sc0 = MFMA32(*(const bf16x8*)(kr0 + off), qf[c], sc0);
      sc1 = MFMA32(*(const bf16x8*)(kr1 + off), qf[c], sc1);
    }
    __builtin_amdgcn_s_setprio(0);

    // online softmax (log2 domain), defer-max: rescale only on real growth
    float mx[8];
    #pragma unroll
    for (int i = 0; i < 8; ++i)
      mx[i] = fmaxf(fmaxf(sc0[i], sc0[i + 8]), fmaxf(sc1[i], sc1[i + 8]));
    float tm = fmaxf(fmaxf(fmaxf(mx[0], mx[1]), fmaxf(mx[2], mx[3])),
                     fmaxf(fmaxf(mx[4], mx[5]), fmaxf(mx[6], mx[7])));
    tm = fmaxf(tm, __shfl_xor(tm, 32, 64));
    if (__any(tm > m_run + 8.0f)) {
      const float mn = fmaxf(m_run, tm);
      const float es = EXP2(m_run - mn);   // 0 on first tile
      m_run = mn;
      l_run *= es;
      #pragma unroll
      for (int q = 0; q < 4; ++q)
        #pragma unroll
        for (int rr = 0; rr < 4; ++rr) {
          const float e = __shfl(es, 8 * q + 4 * hi + rr, 32);
          accO0[q * 4 + rr] *= e;
          accO1[q * 4 + rr] *= e;
        }
    }
    #pragma unroll
    for (int i = 0; i < 16; ++i) {
      sc0[i] = EXP2(sc0[i] - m_run);
      sc1[i] = EXP2(sc1[i] - m_run);
    }
    float p0s = 0.f, p1s = 0.f, p2s = 0.f, p3s = 0.f;
    #pragma unroll
    for (int i = 0; i < 16; i += 4) {
      p0s += sc0[i]     + sc1[i];
      p1s += sc0[i + 1] + sc1[i + 1];
      p2s += sc0[i + 2] + sc1[i + 2];
      p3s += sc0[i + 3] + sc1[i + 3];
    }
    float rs = (p0s + p1s) + (p2s + p3s);
    rs += __shfl_xor(rs, 32, 64);
    l_run += rs;

    // P -> bf16 A-frags: frag(c)[j] = P[t][c*16 + hi*8 + j]
    unsigned wA0[4], wB0[4], wA1[4], wB1[4];
    #pragma unroll
    for (int g = 0; g < 4; ++g) {
      wA0[g] = pack2(sc0[4 * g],     sc0[4 * g + 1]);
      wB0[g] = pack2(sc0[4 * g + 2], sc0[4 * g + 3]);
      wA1[g] = pack2(sc1[4 * g],     sc1[4 * g + 1]);
      wB1[g] = pack2(sc1[4 * g + 2], sc1[4 * g + 3]);
    }
    bf16x8 pa[2][2];
    #pragma unroll
    for (int sb = 0; sb < 2; ++sb) {
      const unsigned* WA = sb ? wA1 : wA0;
      const unsigned* WB = sb ? wB1 : wB0;
      #pragma unroll
      for (int c = 0; c < 2; ++c) {
        unsigned a0 = WA[2 * c], a1 = WA[2 * c + 1];
        unsigned b0 = WB[2 * c], b1 = WB[2 * c + 1];
        unsigned xa0 = __shfl_xor(a0, 32, 64);
        unsigned xa1 = __shfl_xor(a1, 32, 64);
        unsigned xb0 = __shfl_xor(b0, 32, 64);
        unsigned xb1 = __shfl_xor(b1, 32, 64);
        union { unsigned u[4]; bf16x8 v; } uu;
        uu.u[0] = hi ? xa1 : a0;
        uu.u[1] = hi ? xb1 : b0;
        uu.u[2] = hi ? a1 : xa0;
        uu.u[3] = hi ? b1 : xb0;
        pa[sb][c] = uu.v;
      }
    }

    // PV: O[t][d] += P . V, B-frag from V^T tile
    const char* vr0 = cur + 8192 + tl * 128;
    const char* vr1 = cur + 8192 + (32 + tl) * 128;
    __builtin_amdgcn_s_setprio(1);
    #pragma unroll
    for (int sb = 0; sb < 2; ++sb)
      #pragma unroll
      for (int c = 0; c < 2; ++c) {
        const int off = (((sb * 4 + c * 2 + hi) ^ (tl & 7)) << 4);
        accO0 = MFMA32(pa[sb][c], *(const bf16x8*)(vr0 + off), accO0);
        accO1 = MFMA32(pa[sb][c], *(const bf16x8*)(vr1 + off), accO1);
      }
    __builtin_amdgcn_s_setprio(0);

    // write next tile (regs have landed by now; only lgkm drain at barrier)
    if (st + 1 < 32) {
      *(bf16x8*)(nxt + ko0) = rk0;
      *(bf16x8*)(nxt + ko0 + 4096) = rk1;
      *(bf16x8*)(nxt + 8192 + ko0) = rv0;
      *(bf16x8*)(nxt + 8192 + ko0 + 4096) = rv1;
    }
  }

  // epilogue: 1/l broadcast via shfl (row = 8q+4hi+rr)
  const float linv = 1.0f / l_run;
  const int b2 = bh >> 4, h = bh & 15;
  #pragma unroll
  for (int q = 0; q < 4; ++q)
    #pragma unroll
    for (int rr = 0; rr < 4; ++rr) {
      const float lv = __shfl(linv, 8 * q + 4 * hi + rr, 32);
      const int t = t0w + 8 * q + 4 * hi + rr;
      __bf16* cp = ctx + ((size_t)t * Bn + b2) * En + h * 64 + tl;
      cp[0]  = (__bf16)(accO0[q * 4 + rr] * lv);
      cp[32] = (__bf16)(accO1[q * 4 + rr] * lv);
    }
  if (hi == 0) {
    const int t = t0w + tl;
    f32x2 stv; stv[0] = m_run; stv[1] = l_run;
    *reinterpret_cast<f32x2*>(&stats[((size_t)bh * Tn + t) * 2]) = stv;
  }
}

// ---------------------------------------------------------------------------
// Kernel 3: avg attention weights (recompute QK^T; log2-domain stats).
// ---------------------------------------------------------------------------
__global__ __launch_bounds__(256)
void k_avgw(const __bf16* __restrict__ q_ws, const __bf16* __restrict__ k_ws,
            const float* __restrict__ stats, float* __restrict__ avg_out)
{
  __shared__ __align__(16) char q_sm[8192];
  __shared__ __align__(16) char k_sm[8192];
  __shared__ __align__(16) float adj_sm[16][64];

  const int tid = threadIdx.x;
  const int lane = tid & 63, w = tid >> 6;
  const int tl = lane & 31, hi = lane >> 5;
  const int b2 = blockIdx.x >> 10;
  const int tt = (blockIdx.x >> 5) & 31;
  const int ss = blockIdx.x & 31;
  const int thalf = (w >> 1) * 32, shalf = (w & 1) * 32;

  #pragma unroll
  for (int it = 0; it < 4; ++it) {
    int idx = tid + it * 256;
    int h = idx >> 6, trow = idx & 63;
    f32x2 sv = *(const f32x2*)&stats[(((size_t)(b2 * Hn + h)) * Tn + tt * 64 + trow) * 2];
    adj_sm[h][trow] = sv[0] + LOG2(16.0f * sv[1]);
  }

  const size_t hstride = (size_t)Tn * Dn;
  const __bf16* qb = q_ws + ((size_t)(b2 * Hn) * Tn + tt * 64) * Dn;
  const __bf16* kb = k_ws + ((size_t)(b2 * Hn) * Tn + ss * 64) * Dn;

  const int r0 = tid >> 3, s0 = tid & 7;
  const int ldso = ((s0 ^ (r0 & 7)) << 4);
  const int ko0 = r0 * 128 + ldso, ko1 = ko0 + 32 * 128;

  bf16x8 rq0 = *(const bf16x8*)(qb + r0 * 64 + s0 * 8);
  bf16x8 rq1 = *(const bf16x8*)(qb + (r0 + 32) * 64 + s0 * 8);
  bf16x8 rk0 = *(const bf16x8*)(kb + r0 * 64 + s0 * 8);
  bf16x8 rk1 = *(const bf16x8*)(kb + (r0 + 32) * 64 + s0 * 8);

  f32x16 avg;
  #pragma unroll
  for (int i = 0; i < 16; ++i) avg[i] = 0.f;

  const char* qr = q_sm + (thalf + tl) * 128;
  const char* kr = k_sm + (shalf + tl) * 128;

  for (int h = 0; h < Hn; ++h) {
    __syncthreads();
    *(bf16x8*)(q_sm + ko0) = rq0;
    *(bf16x8*)(q_sm + ko1) = rq1;
    *(bf16x8*)(k_sm + ko0) = rk0;
    *(bf16x8*)(k_sm + ko1) = rk1;
    __syncthreads();
    if (h + 1 < Hn) {
      const __bf16* qn = qb + (size_t)(h + 1) * hstride;
      const __bf16* kn = kb + (size_t)(h + 1) * hstride;
      rq0 = *(const bf16x8*)(qn + r0 * 64 + s0 * 8);
      rq1 = *(const bf16x8*)(qn + (r0 + 32) * 64 + s0 * 8);
      rk0 = *(const bf16x8*)(kn + r0 * 64 + s0 * 8);
      rk1 = *(const bf16x8*)(kn + (r0 + 32) * 64 + s0 * 8);
    }

    f32x16 sc;
    #pragma unroll
    for (int i = 0; i < 16; ++i) sc[i] = 0.f;
    #pragma unroll
    for (int c = 0; c < 4; ++c) {
      const int off = (((2 * c + hi) ^ (tl & 7)) << 4);
      sc = MFMA32(*(const bf16x8*)(qr + off), *(const bf16x8*)(kr + off), sc);
    }

    #pragma unroll
    for (int q = 0; q < 4; ++q) {
      f32x4 ad = *(const f32x4*)&adj_sm[h][thalf + 8 * q + 4 * hi];
      #pragma unroll
      for (int r = 0; r < 4; ++r)
        avg[q * 4 + r] += EXP2(sc[q * 4 + r] - ad[r]);
    }
  }

  #pragma unroll
  for (int q = 0; q < 4; ++q)
    #pragma unroll
    for (int r = 0; r < 4; ++r) {
      int t = tt * 64 + thalf + 8 * q + 4 * hi + r;
      int s = ss * 64 + shalf + tl;
      avg_out[((size_t)(b2 * Tn + t)) * Tn + s] = avg[q * 4 + r];
    }
}

// ---------------------------------------------------------------------------
// Kernel 4: out projection, bf16 operands via global_load_lds, fp32 out.
// ---------------------------------------------------------------------------
__global__ __launch_bounds__(256)
void k_outproj(const __bf16* __restrict__ ctx, const __bf16* __restrict__ W,
               const float* __restrict__ bias, float* __restrict__ out)
{
  __shared__ __align__(16) char a_lds[8192];
  __shared__ __align__(16) char b_lds[8192];
  const int tid = threadIdx.x;
  const int lane = tid & 63, w = tid >> 6;
  const int wr = w >> 1, wc = w & 1;
  const int ag = lane >> 4, lr = lane & 15;
  const int mBase = blockIdx.x * 128;
  const int oBase = blockIdx.y * 128;
  const __bf16* Wt = W + (size_t)oBase * En;

  const int gA = w;
  char* laA0 = a_lds + gA * 2048;
  char* laA1 = a_lds + gA * 2048 + 1024;
  char* lbA0 = b_lds + gA * 2048;
  char* lbA1 = b_lds + gA * 2048 + 1024;
  const __bf16* pa0 = ctx + (size_t)(mBase + lane) * En + gA * 8;
  const __bf16* pa1 = ctx + (size_t)(mBase + 64 + lane) * En + gA * 8;
  const __bf16* pb0 = Wt + (size_t)(lane) * En + gA * 8;
  const __bf16* pb1 = Wt + (size_t)(64 + lane) * En + gA * 8;

  f32x4 acc[4][4];
  #pragma unroll
  for (int i = 0; i < 4; ++i)
    #pragma unroll
    for (int j = 0; j < 4; ++j) { f32x4 z = {0.f,0.f,0.f,0.f}; acc[i][j] = z; }

  for (int kk = 0; kk < En; kk += 32) {
    __syncthreads();
    gload_lds16(pa0 + kk, laA0);
    gload_lds16(pa1 + kk, laA1);
    gload_lds16(pb0 + kk, lbA0);
    gload_lds16(pb1 + kk, lbA1);
    __syncthreads();
    bf16x8 af[4], bfr[4];
    #pragma unroll
    for (int mb = 0; mb < 4; ++mb)
      af[mb] = *(const bf16x8*)(a_lds + ag * 2048 + (wr * 64 + mb * 16 + lr) * 16);
    #pragma unroll
    for (int nb = 0; nb < 4; ++nb)
      bfr[nb] = *(const bf16x8*)(b_lds + ag * 2048 + (wc * 64 + nb * 16 + lr) * 16);
    #pragma unroll
    for (int mb = 0; mb < 4; ++mb)
      #pragma unroll
      for (int nb = 0; nb < 4; ++nb)
        acc[mb][nb] = MFMA16(af[mb], bfr[nb], acc[mb][nb]);
  }

  #pragma unroll
  for (int nb = 0; nb < 4; ++nb) {
    int o = oBase + wc * 64 + nb * 16 + lr;
    float bv = bias[o];
    #pragma unroll
    for (int mb = 0; mb < 4; ++mb)
      #pragma unroll
      for (int r = 0; r < 4; ++r) {
        int i = mBase + wr * 64 + mb * 16 + ag * 4 + r;
        out[(size_t)i * En + o] = acc[mb][nb][r] + bv;
      }
  }
}

// ---------------------------------------------------------------------------
extern "C" void kernel_launch(void* const* d_in, const int* in_sizes, int n_in,
                              void* d_out, int out_size, void* d_ws, size_t ws_size,
                              hipStream_t stream)
{
  (void)in_sizes; (void)n_in; (void)out_size; (void)ws_size;
  const float* query = (const float*)d_in[0];
  const float* key   = (const float*)d_in[1];
  const float* value = (const float*)d_in[2];
  const float* in_w  = (const float*)d_in[3];
  const float* in_b  = (const float*)d_in[4];
  const float* out_w = (const float*)d_in[5];
  const float* out_b = (const float*)d_in[6];

  float* attn_out = (float*)d_out;                                 // [T,B,E]
  float* avg_out  = (float*)d_out + (size_t)Tn * Bn * En;          // [B,T,S]

  char* ws = (char*)d_ws;
  const size_t MB = 1u << 20;
  __bf16* q_ws  = (__bf16*)(ws);                    // [B,H,T,D] bf16, 8 MB
  __bf16* k_ws  = (__bf16*)(ws + 8 * MB);           // 8 MB
  __bf16* v_ws  = (__bf16*)(ws + 16 * MB);          // 8 MB
  __bf16* vt_ws = (__bf16*)(ws + 24 * MB);          // 8 MB (aliases xq_bf)
  __bf16* ctx   = (__bf16*)(ws + 32 * MB);          // 8 MB (aliases xk_bf)
  float*  stats = (float*)(ws + 40 * MB);           // 512 KB
  __bf16* xq_bf = vt_ws;                            // dead before transpose
  __bf16* xk_bf = ctx;                              // dead before flash
  __bf16* xv_bf = (__bf16*)(ws + 40 * MB + 512 * 1024);   // 8 MB
  __bf16* w3_bf = (__bf16*)(ws + 48 * MB + 512 * 1024);   // 6 MB
  __bf16* wo_bf = (__bf16*)(ws + 54 * MB + 512 * 1024);   // 2 MB

  k_cvt<<<8192, 256, 0, stream>>>(query, key, value, in_w, out_w,
                                  xq_bf, xk_bf, xv_bf, w3_bf, wo_bf);
  k_qkv<<<dim3(32, 24), 256, 0, stream>>>(xq_bf, xk_bf, xv_bf, w3_bf, in_b,
                                          q_ws, k_ws, v_ws);
  k_transpose_v<<<1024, 256, 0, stream>>>(v_ws, vt_ws);
  k_flash<<<512, 256, 0, stream>>>(q_ws, k_ws, vt_ws, ctx, stats);
  k_avgw<<<2048, 256, 0, stream>>>(q_ws, k_ws, stats, avg_out);
  k_outproj<<<dim3(32, 8), 256, 0, stream>>>(ctx, wo_bf, out_b, attn_out);
}

// Round 6
// 201.203 us; speedup vs baseline: 1.0685x; 1.0560x over previous
//
#include <hip/hip_runtime.h>
#include <hip/hip_bf16.h>

typedef float  f32x2  __attribute__((ext_vector_type(2)));
typedef float  f32x4  __attribute__((ext_vector_type(4)));
typedef float  f32x16 __attribute__((ext_vector_type(16)));
typedef __bf16 bf16x8 __attribute__((ext_vector_type(8)));

#define MFMA16(A,B,C) __builtin_amdgcn_mfma_f32_16x16x32_bf16((A),(B),(C),0,0,0)
#define MFMA32(A,B,C) __builtin_amdgcn_mfma_f32_32x32x16_bf16((A),(B),(C),0,0,0)
#define EXP2(x) __builtin_amdgcn_exp2f(x)
#define LOG2(x) __builtin_amdgcn_logf(x)

static constexpr int Tn = 2048, Bn = 2, En = 1024, Hn = 16, Dn = 64;
// Q is pre-scaled by (1/sqrt(D)) * log2(e): all score math is in log2 domain.
static constexpr float kQScale = 0.125f * 1.4426950408889634f;

static __device__ __forceinline__ unsigned pack2(float a, float b) {
  union { __bf16 h[2]; unsigned u; } un;
  un.h[0] = (__bf16)a; un.h[1] = (__bf16)b;
  return un.u;
}

// async global->LDS, 16B per lane; LDS dest is wave-uniform base + lane*16
static __device__ __forceinline__ void gload_lds16(const void* g, void* l) {
  __builtin_amdgcn_global_load_lds(
      (const __attribute__((address_space(1))) void*)g,
      (__attribute__((address_space(3))) void*)l, 16, 0, 0);
}

// ---------------------------------------------------------------------------
// Kernel 0: fp32 -> bf16 convert of Q/K/V inputs and both weight matrices.
// ---------------------------------------------------------------------------
__global__ __launch_bounds__(256)
void k_cvt(const float* __restrict__ q, const float* __restrict__ k,
           const float* __restrict__ v, const float* __restrict__ w3,
           const float* __restrict__ wo,
           __bf16* __restrict__ qb, __bf16* __restrict__ kb,
           __bf16* __restrict__ vb, __bf16* __restrict__ w3b,
           __bf16* __restrict__ wob)
{
  const size_t g = (size_t)blockIdx.x * 256 + threadIdx.x;  // granule id
  const float* src;
  __bf16* dst;
  size_t off;
  if (g < 524288)        { src = q;  dst = qb;  off = g; }
  else if (g < 1048576)  { src = k;  dst = kb;  off = g - 524288; }
  else if (g < 1572864)  { src = v;  dst = vb;  off = g - 1048576; }
  else if (g < 1966080)  { src = w3; dst = w3b; off = g - 1572864; }
  else                   { src = wo; dst = wob; off = g - 1966080; }
  const float* p = src + off * 8;
  f32x4 a = *reinterpret_cast<const f32x4*>(p);
  f32x4 b = *reinterpret_cast<const f32x4*>(p + 4);
  bf16x8 o;
  #pragma unroll
  for (int e = 0; e < 4; ++e) { o[e] = (__bf16)a[e]; o[e + 4] = (__bf16)b[e]; }
  *reinterpret_cast<bf16x8*>(dst + off * 8) = o;
}

// ---------------------------------------------------------------------------
// Kernel 1: fused QKV in-projection, 2-phase prefetch double-buffered
// global_load_lds staging (issue next tile before compute, 1 barrier/K-step).
// ---------------------------------------------------------------------------
__global__ __launch_bounds__(256)
void k_qkv(const __bf16* __restrict__ Xq, const __bf16* __restrict__ Xk,
           const __bf16* __restrict__ Xv, const __bf16* __restrict__ W,
           const float* __restrict__ bias,
           __bf16* __restrict__ q_ws, __bf16* __restrict__ k_ws,
           __bf16* __restrict__ v_ws)
{
  __shared__ __align__(16) char a_lds[2][8192];
  __shared__ __align__(16) char b_lds[2][8192];
  const int tid = threadIdx.x;
  const int lane = tid & 63, w = tid >> 6;
  const int wr = w >> 1, wc = w & 1;
  const int ag = lane >> 4, lr = lane & 15;
  const int mBase = blockIdx.x * 128;
  const int oBase = blockIdx.y * 128;
  const int which = blockIdx.y >> 3;
  const __bf16* X  = (which == 0) ? Xq : ((which == 1) ? Xk : Xv);
  const __bf16* Wt = W + (size_t)oBase * En;
  __bf16* dst = (which == 0) ? q_ws : ((which == 1) ? k_ws : v_ws);
  const float oscale = (which == 0) ? kQScale : 1.0f;

  const int gA = w;                             // wave owns k-granule w
  const __bf16* pa0 = X  + (size_t)(mBase + lane) * En + gA * 8;
  const __bf16* pa1 = X  + (size_t)(mBase + 64 + lane) * En + gA * 8;
  const __bf16* pb0 = Wt + (size_t)(lane) * En + gA * 8;
  const __bf16* pb1 = Wt + (size_t)(64 + lane) * En + gA * 8;

  f32x4 acc[4][4];
  #pragma unroll
  for (int i = 0; i < 4; ++i)
    #pragma unroll
    for (int j = 0; j < 4; ++j) { f32x4 z = {0.f, 0.f, 0.f, 0.f}; acc[i][j] = z; }

  // prologue: stage K-step 0 into buf 0
  gload_lds16(pa0, &a_lds[0][gA * 2048]);
  gload_lds16(pa1, &a_lds[0][gA * 2048 + 1024]);
  gload_lds16(pb0, &b_lds[0][gA * 2048]);
  gload_lds16(pb1, &b_lds[0][gA * 2048 + 1024]);
  __syncthreads();

  for (int kt = 0; kt < 32; ++kt) {
    const int cur = kt & 1, nxt = cur ^ 1;
    if (kt + 1 < 32) {                 // issue next tile BEFORE compute
      const int kk = (kt + 1) * 32;
      gload_lds16(pa0 + kk, &a_lds[nxt][gA * 2048]);
      gload_lds16(pa1 + kk, &a_lds[nxt][gA * 2048 + 1024]);
      gload_lds16(pb0 + kk, &b_lds[nxt][gA * 2048]);
      gload_lds16(pb1 + kk, &b_lds[nxt][gA * 2048 + 1024]);
    }
    bf16x8 af[4], bfr[4];
    #pragma unroll
    for (int mb = 0; mb < 4; ++mb)
      af[mb] = *(const bf16x8*)(&a_lds[cur][ag * 2048 + (wr * 64 + mb * 16 + lr) * 16]);
    #pragma unroll
    for (int nb = 0; nb < 4; ++nb)
      bfr[nb] = *(const bf16x8*)(&b_lds[cur][ag * 2048 + (wc * 64 + nb * 16 + lr) * 16]);
    #pragma unroll
    for (int mb = 0; mb < 4; ++mb)
      #pragma unroll
      for (int nb = 0; nb < 4; ++nb)
        acc[mb][nb] = MFMA16(af[mb], bfr[nb], acc[mb][nb]);
    __syncthreads();                   // drains this iter's glls (vmcnt0+lgkm)
  }

  #pragma unroll
  for (int nb = 0; nb < 4; ++nb) {
    int oG = oBase + wc * 64 + nb * 16 + lr;
    float bv = bias[oG];
    int oS = oG & (En - 1);
    int h = oS >> 6, d = oS & 63;
    #pragma unroll
    for (int mb = 0; mb < 4; ++mb)
      #pragma unroll
      for (int r = 0; r < 4; ++r) {
        int i = mBase + wr * 64 + mb * 16 + ag * 4 + r;
        int t = i >> 1, b2 = i & 1;
        dst[(((size_t)(b2 * Hn + h)) * Tn + t) * Dn + d] =
            (__bf16)((acc[mb][nb][r] + bv) * oscale);
      }
  }
}

// ---------------------------------------------------------------------------
// Kernel 1b: V [bh, T, D] -> V^T [bh, D, T]  (bf16), LDS tile transpose.
// ---------------------------------------------------------------------------
__global__ __launch_bounds__(256)
void k_transpose_v(const __bf16* __restrict__ v_ws, __bf16* __restrict__ vt_ws)
{
  __shared__ __bf16 tile[64][72];
  const int bh = blockIdx.x >> 5;
  const int tt = blockIdx.x & 31;
  const int tid = threadIdx.x;
  const __bf16* src = v_ws + ((size_t)bh * Tn + tt * 64) * Dn;
  #pragma unroll
  for (int it = 0; it < 2; ++it) {
    int gi = tid + it * 256;
    int row = gi >> 3, gg = gi & 7;
    *reinterpret_cast<bf16x8*>(&tile[row][gg * 8]) =
        *reinterpret_cast<const bf16x8*>(src + row * Dn + gg * 8);
  }
  __syncthreads();
  __bf16* dst = vt_ws + (size_t)bh * Dn * Tn + tt * 64;
  #pragma unroll
  for (int it = 0; it < 2; ++it) {
    int gi = tid + it * 256;
    int drow = gi >> 3, tg = gi & 7;
    bf16x8 vv;
    #pragma unroll
    for (int e = 0; e < 8; ++e) vv[e] = tile[tg * 8 + e][drow];
    *reinterpret_cast<bf16x8*>(dst + (size_t)drow * Tn + tg * 8) = vv;
  }
}

// ---------------------------------------------------------------------------
// Kernel 2: flash attention, swapped-operand 32x32 MFMA, log2 domain.
// l via MFMA against ones (row layout == accO), permlane32_swap P-transpose,
// defer-max, dbuf K/V (1 barrier/iter), setprio. Emits adj = m + log2(16 l).
// ---------------------------------------------------------------------------
__global__ __launch_bounds__(256, 2)
void k_flash(const __bf16* __restrict__ q_ws, const __bf16* __restrict__ k_ws,
             const __bf16* __restrict__ vt_ws, __bf16* __restrict__ ctx,
             float* __restrict__ adj_g)
{
  __shared__ __align__(16) char kv_sm[2 * 16384];  // [buf][K 8KB | V 8KB]

  const int tid = threadIdx.x;
  const int lane = tid & 63, w = tid >> 6;
  const int tl = lane & 31, hi = lane >> 5;
  const int bh = blockIdx.x >> 4;
  const int qt = blockIdx.x & 15;
  const int t0w = qt * 128 + w * 32;

  const __bf16* kbase  = k_ws + (size_t)bh * Tn * Dn;
  const __bf16* vtbase = vt_ws + (size_t)bh * Dn * Tn;

  // Q B-frags: lane holds Q[t0w+tl][c*16 + hi*8 + j]
  bf16x8 qf[4];
  {
    const __bf16* qrow = q_ws + ((size_t)bh * Tn + t0w + tl) * Dn + hi * 8;
    #pragma unroll
    for (int c = 0; c < 4; ++c)
      qf[c] = *reinterpret_cast<const bf16x8*>(qrow + c * 16);
  }

  // all-ones bf16 B-frag for the l-accumulating MFMA
  union { unsigned u[4]; bf16x8 v; } onu;
  #pragma unroll
  for (int j = 0; j < 4; ++j) onu.u[j] = 0x3F803F80u;
  const bf16x8 kOne = onu.v;

  f32x16 accO0, accO1, accL;
  #pragma unroll
  for (int i = 0; i < 16; ++i) { accO0[i] = 0.f; accO1[i] = 0.f; accL[i] = 0.f; }
  float m_run = -INFINITY;

  // staging: thread owns granule s0 of rows r0 and r0+32 (K and V)
  const int r0 = tid >> 3, s0 = tid & 7;
  const int ldso = ((s0 ^ (r0 & 7)) << 4);
  const int ko0 = r0 * 128 + ldso;              // +4096 => rows 32..63

  bf16x8 rk0 = *(const bf16x8*)(kbase + r0 * 64 + s0 * 8);
  bf16x8 rk1 = *(const bf16x8*)(kbase + (r0 + 32) * 64 + s0 * 8);
  bf16x8 rv0 = *(const bf16x8*)(vtbase + (size_t)r0 * Tn + s0 * 8);
  bf16x8 rv1 = *(const bf16x8*)(vtbase + (size_t)(r0 + 32) * Tn + s0 * 8);
  *(bf16x8*)(kv_sm + ko0) = rk0;
  *(bf16x8*)(kv_sm + ko0 + 4096) = rk1;
  *(bf16x8*)(kv_sm + 8192 + ko0) = rv0;
  *(bf16x8*)(kv_sm + 8192 + ko0 + 4096) = rv1;

  for (int st = 0; st < 32; ++st) {
    __syncthreads();
    const char* cur = kv_sm + (st & 1) * 16384;
    char* nxt = kv_sm + ((st + 1) & 1) * 16384;
    if (st + 1 < 32) {   // issue next tile's loads; land during compute (T14)
      const __bf16* kn = kbase + (size_t)(st + 1) * 64 * Dn;
      const __bf16* vn = vtbase + (st + 1) * 64;
      rk0 = *(const bf16x8*)(kn + r0 * 64 + s0 * 8);
      rk1 = *(const bf16x8*)(kn + (r0 + 32) * 64 + s0 * 8);
      rv0 = *(const bf16x8*)(vn + (size_t)r0 * Tn + s0 * 8);
      rv1 = *(const bf16x8*)(vn + (size_t)(r0 + 32) * Tn + s0 * 8);
    }

    // QK^T (swapped): sc{0,1}[reg] = S[s = ss*32 + 8*(reg>>2)+4*hi+(reg&3)][tl]
    f32x16 sc0, sc1;
    #pragma unroll
    for (int i = 0; i < 16; ++i) { sc0[i] = 0.f; sc1[i] = 0.f; }
    const char* kr0 = cur + tl * 128;
    const char* kr1 = cur + (32 + tl) * 128;
    __builtin_amdgcn_s_setprio(1);
    #pragma unroll
    for (int c = 0; c < 4; ++c) {
      const int off = (((2 * c + hi) ^ (tl & 7)) << 4);
      sc0 = MFMA32(*(const bf16x8*)(kr0 + off), qf[c], sc0);
      sc1 = MFMA32(*(const bf16x8*)(kr1 + off), qf[c], sc1);
    }
    __builtin_amdgcn_s_setprio(0);

    // online softmax (log2 domain), defer-max: rescale only on real growth
    float mx[8];
    #pragma unroll
    for (int i = 0; i < 8; ++i)
      mx[i] = fmaxf(fmaxf(sc0[i], sc0[i + 8]), fmaxf(sc1[i], sc1[i + 8]));
    float tm = fmaxf(fmaxf(fmaxf(mx[0], mx[1]), fmaxf(mx[2], mx[3])),
                     fmaxf(fmaxf(mx[4], mx[5]), fmaxf(mx[6], mx[7])));
    tm = fmaxf(tm, __shfl_xor(tm, 32, 64));
    if (__any(tm > m_run + 8.0f)) {
      const float mn = fmaxf(m_run, tm);
      const float es = EXP2(m_run - mn);   // 0 on first tile
      m_run = mn;
      #pragma unroll
      for (int q = 0; q < 4; ++q)
        #pragma unroll
        for (int rr = 0; rr < 4; ++rr) {
          const float e = __shfl(es, 8 * q + 4 * hi + rr, 32);
          accO0[q * 4 + rr] *= e;
          accO1[q * 4 + rr] *= e;
          accL[q * 4 + rr] *= e;
        }
    }
    #pragma unroll
    for (int i = 0; i < 16; ++i) {
      sc0[i] = EXP2(sc0[i] - m_run);
      sc1[i] = EXP2(sc1[i] - m_run);
    }

    // P -> bf16 A-frags via v_permlane32_swap_b32 (T12):
    // frag(sb,c)[word0..3] = s-pairs {16c+hi*8+0,1},{+2,3},{+4,5},{+6,7}
    unsigned wA0[4], wB0[4], wA1[4], wB1[4];
    #pragma unroll
    for (int g = 0; g < 4; ++g) {
      wA0[g] = pack2(sc0[4 * g],     sc0[4 * g + 1]);
      wB0[g] = pack2(sc0[4 * g + 2], sc0[4 * g + 3]);
      wA1[g] = pack2(sc1[4 * g],     sc1[4 * g + 1]);
      wB1[g] = pack2(sc1[4 * g + 2], sc1[4 * g + 3]);
    }
    bf16x8 pa[2][2];
    #pragma unroll
    for (int sb = 0; sb < 2; ++sb) {
      const unsigned* WA = sb ? wA1 : wA0;
      const unsigned* WB = sb ? wB1 : wB0;
      #pragma unroll
      for (int c = 0; c < 2; ++c) {
        unsigned w0 = WA[2 * c], w2 = WA[2 * c + 1];
        unsigned w1 = WB[2 * c], w3 = WB[2 * c + 1];
        asm("v_permlane32_swap_b32 %0, %1" : "+v"(w0), "+v"(w2));
        asm("v_permlane32_swap_b32 %0, %1" : "+v"(w1), "+v"(w3));
        union { unsigned u[4]; bf16x8 v; } uu;
        uu.u[0] = w0; uu.u[1] = w1; uu.u[2] = w2; uu.u[3] = w3;
        pa[sb][c] = uu.v;
      }
    }

    // PV: O[t][d] += P . V;  l[t] += P . 1 (row layout identical to accO)
    const char* vr0 = cur + 8192 + tl * 128;
    const char* vr1 = cur + 8192 + (32 + tl) * 128;
    __builtin_amdgcn_s_setprio(1);
    #pragma unroll
    for (int sb = 0; sb < 2; ++sb)
      #pragma unroll
      for (int c = 0; c < 2; ++c) {
        const int off = (((sb * 4 + c * 2 + hi) ^ (tl & 7)) << 4);
        accO0 = MFMA32(pa[sb][c], *(const bf16x8*)(vr0 + off), accO0);
        accO1 = MFMA32(pa[sb][c], *(const bf16x8*)(vr1 + off), accO1);
        accL  = MFMA32(pa[sb][c], kOne, accL);
      }
    __builtin_amdgcn_s_setprio(0);

    // write next tile (regs landed during compute)
    if (st + 1 < 32) {
      *(bf16x8*)(nxt + ko0) = rk0;
      *(bf16x8*)(nxt + ko0 + 4096) = rk1;
      *(bf16x8*)(nxt + 8192 + ko0) = rv0;
      *(bf16x8*)(nxt + 8192 + ko0 + 4096) = rv1;
    }
  }

  // epilogue: per-element 1/l is already in matching row layout
  const int b2 = bh >> 4, h = bh & 15;
  float adjv[16];
  #pragma unroll
  for (int q = 0; q < 4; ++q)
    #pragma unroll
    for (int rr = 0; rr < 4; ++rr) {
      const int j = q * 4 + rr;
      const float lv = 1.0f / accL[j];
      const int t = t0w + 8 * q + 4 * hi + rr;
      __bf16* cp = ctx + ((size_t)t * Bn + b2) * En + h * 64 + tl;
      cp[0]  = (__bf16)(accO0[j] * lv);
      cp[32] = (__bf16)(accO1[j] * lv);
      const float mrow = __shfl(m_run, 8 * q + 4 * hi + rr, 32);
      adjv[j] = mrow + LOG2(16.0f * accL[j]);
    }
  if (tl == 0) {
    #pragma unroll
    for (int q = 0; q < 4; ++q)
      #pragma unroll
      for (int rr = 0; rr < 4; ++rr) {
        const int t = t0w + 8 * q + 4 * hi + rr;
        adj_g[(size_t)bh * Tn + t] = adjv[q * 4 + rr];
      }
  }
}

// ---------------------------------------------------------------------------
// Kernel 3: avg attention weights (recompute QK^T; adj precomputed by flash).
// Double-buffered Q/K LDS, 1 barrier per head.
// ---------------------------------------------------------------------------
__global__ __launch_bounds__(256)
void k_avgw(const __bf16* __restrict__ q_ws, const __bf16* __restrict__ k_ws,
            const float* __restrict__ adj_g, float* __restrict__ avg_out)
{
  __shared__ __align__(16) char q_sm[2][8192];
  __shared__ __align__(16) char k_sm[2][8192];
  __shared__ __align__(16) float adj_sm[16][64];

  const int tid = threadIdx.x;
  const int lane = tid & 63, w = tid >> 6;
  const int tl = lane & 31, hi = lane >> 5;
  const int b2 = blockIdx.x >> 10;
  const int tt = (blockIdx.x >> 5) & 31;
  const int ss = blockIdx.x & 31;
  const int thalf = (w >> 1) * 32, shalf = (w & 1) * 32;

  #pragma unroll
  for (int it = 0; it < 4; ++it) {
    int idx = tid + it * 256;
    int h = idx >> 6, trow = idx & 63;
    adj_sm[h][trow] = adj_g[((size_t)(b2 * Hn + h)) * Tn + tt * 64 + trow];
  }

  const size_t hstride = (size_t)Tn * Dn;
  const __bf16* qb = q_ws + ((size_t)(b2 * Hn) * Tn + tt * 64) * Dn;
  const __bf16* kb = k_ws + ((size_t)(b2 * Hn) * Tn + ss * 64) * Dn;

  const int r0 = tid >> 3, s0 = tid & 7;
  const int ldso = ((s0 ^ (r0 & 7)) << 4);
  const int ko0 = r0 * 128 + ldso;               // +4096 => rows 32..63

  bf16x8 rq0 = *(const bf16x8*)(qb + r0 * 64 + s0 * 8);
  bf16x8 rq1 = *(const bf16x8*)(qb + (r0 + 32) * 64 + s0 * 8);
  bf16x8 rk0 = *(const bf16x8*)(kb + r0 * 64 + s0 * 8);
  bf16x8 rk1 = *(const bf16x8*)(kb + (r0 + 32) * 64 + s0 * 8);
  *(bf16x8*)(q_sm[0] + ko0) = rq0;
  *(bf16x8*)(q_sm[0] + ko0 + 4096) = rq1;
  *(bf16x8*)(k_sm[0] + ko0) = rk0;
  *(bf16x8*)(k_sm[0] + ko0 + 4096) = rk1;

  f32x16 avg;
  #pragma unroll
  for (int i = 0; i < 16; ++i) avg[i] = 0.f;

  for (int h = 0; h < Hn; ++h) {
    __syncthreads();
    const char* qc = q_sm[h & 1];
    const char* kc = k_sm[h & 1];
    char* qn = q_sm[(h + 1) & 1];
    char* kn = k_sm[(h + 1) & 1];
    if (h + 1 < Hn) {
      const __bf16* qp = qb + (size_t)(h + 1) * hstride;
      const __bf16* kp = kb + (size_t)(h + 1) * hstride;
      rq0 = *(const bf16x8*)(qp + r0 * 64 + s0 * 8);
      rq1 = *(const bf16x8*)(qp + (r0 + 32) * 64 + s0 * 8);
      rk0 = *(const bf16x8*)(kp + r0 * 64 + s0 * 8);
      rk1 = *(const bf16x8*)(kp + (r0 + 32) * 64 + s0 * 8);
    }

    f32x16 sc;
    #pragma unroll
    for (int i = 0; i < 16; ++i) sc[i] = 0.f;
    const char* qr = qc + (thalf + tl) * 128;
    const char* kr = kc + (shalf + tl) * 128;
    #pragma unroll
    for (int c = 0; c < 4; ++c) {
      const int off = (((2 * c + hi) ^ (tl & 7)) << 4);
      sc = MFMA32(*(const bf16x8*)(qr + off), *(const bf16x8*)(kr + off), sc);
    }

    #pragma unroll
    for (int q = 0; q < 4; ++q) {
      f32x4 ad = *(const f32x4*)&adj_sm[h][thalf + 8 * q + 4 * hi];
      #pragma unroll
      for (int r = 0; r < 4; ++r)
        avg[q * 4 + r] += EXP2(sc[q * 4 + r] - ad[r]);
    }

    if (h + 1 < Hn) {
      *(bf16x8*)(qn + ko0) = rq0;
      *(bf16x8*)(qn + ko0 + 4096) = rq1;
      *(bf16x8*)(kn + ko0) = rk0;
      *(bf16x8*)(kn + ko0 + 4096) = rk1;
    }
  }

  #pragma unroll
  for (int q = 0; q < 4; ++q)
    #pragma unroll
    for (int r = 0; r < 4; ++r) {
      int t = tt * 64 + thalf + 8 * q + 4 * hi + r;
      int s = ss * 64 + shalf + tl;
      avg_out[((size_t)(b2 * Tn + t)) * Tn + s] = avg[q * 4 + r];
    }
}

// ---------------------------------------------------------------------------
// Kernel 4: out projection, 2-phase prefetch dbuf gload_lds, fp32 out.
// ---------------------------------------------------------------------------
__global__ __launch_bounds__(256)
void k_outproj(const __bf16* __restrict__ ctx, const __bf16* __restrict__ W,
               const float* __restrict__ bias, float* __restrict__ out)
{
  __shared__ __align__(16) char a_lds[2][8192];
  __shared__ __align__(16) char b_lds[2][8192];
  const int tid = threadIdx.x;
  const int lane = tid & 63, w = tid >> 6;
  const int wr = w >> 1, wc = w & 1;
  const int ag = lane >> 4, lr = lane & 15;
  const int mBase = blockIdx.x * 128;
  const int oBase = blockIdx.y * 128;
  const __bf16* Wt = W + (size_t)oBase * En;

  const int gA = w;
  const __bf16* pa0 = ctx + (size_t)(mBase + lane) * En + gA * 8;
  const __bf16* pa1 = ctx + (size_t)(mBase + 64 + lane) * En + gA * 8;
  const __bf16* pb0 = Wt + (size_t)(lane) * En + gA * 8;
  const __bf16* pb1 = Wt + (size_t)(64 + lane) * En + gA * 8;

  f32x4 acc[4][4];
  #pragma unroll
  for (int i = 0; i < 4; ++i)
    #pragma unroll
    for (int j = 0; j < 4; ++j) { f32x4 z = {0.f,0.f,0.f,0.f}; acc[i][j] = z; }

  gload_lds16(pa0, &a_lds[0][gA * 2048]);
  gload_lds16(pa1, &a_lds[0][gA * 2048 + 1024]);
  gload_lds16(pb0, &b_lds[0][gA * 2048]);
  gload_lds16(pb1, &b_lds[0][gA * 2048 + 1024]);
  __syncthreads();

  for (int kt = 0; kt < 32; ++kt) {
    const int cur = kt & 1, nxt = cur ^ 1;
    if (kt + 1 < 32) {
      const int kk = (kt + 1) * 32;
      gload_lds16(pa0 + kk, &a_lds[nxt][gA * 2048]);
      gload_lds16(pa1 + kk, &a_lds[nxt][gA * 2048 + 1024]);
      gload_lds16(pb0 + kk, &b_lds[nxt][gA * 2048]);
      gload_lds16(pb1 + kk, &b_lds[nxt][gA * 2048 + 1024]);
    }
    bf16x8 af[4], bfr[4];
    #pragma unroll
    for (int mb = 0; mb < 4; ++mb)
      af[mb] = *(const bf16x8*)(&a_lds[cur][ag * 2048 + (wr * 64 + mb * 16 + lr) * 16]);
    #pragma unroll
    for (int nb = 0; nb < 4; ++nb)
      bfr[nb] = *(const bf16x8*)(&b_lds[cur][ag * 2048 + (wc * 64 + nb * 16 + lr) * 16]);
    #pragma unroll
    for (int mb = 0; mb < 4; ++mb)
      #pragma unroll
      for (int nb = 0; nb < 4; ++nb)
        acc[mb][nb] = MFMA16(af[mb], bfr[nb], acc[mb][nb]);
    __syncthreads();
  }

  #pragma unroll
  for (int nb = 0; nb < 4; ++nb) {
    int o = oBase + wc * 64 + nb * 16 + lr;
    float bv = bias[o];
    #pragma unroll
    for (int mb = 0; mb < 4; ++mb)
      #pragma unroll
      for (int r = 0; r < 4; ++r) {
        int i = mBase + wr * 64 + mb * 16 + ag * 4 + r;
        out[(size_t)i * En + o] = acc[mb][nb][r] + bv;
      }
  }
}

// ---------------------------------------------------------------------------
extern "C" void kernel_launch(void* const* d_in, const int* in_sizes, int n_in,
                              void* d_out, int out_size, void* d_ws, size_t ws_size,
                              hipStream_t stream)
{
  (void)in_sizes; (void)n_in; (void)out_size; (void)ws_size;
  const float* query = (const float*)d_in[0];
  const float* key   = (const float*)d_in[1];
  const float* value = (const float*)d_in[2];
  const float* in_w  = (const float*)d_in[3];
  const float* in_b  = (const float*)d_in[4];
  const float* out_w = (const float*)d_in[5];
  const float* out_b = (const float*)d_in[6];

  float* attn_out = (float*)d_out;                                 // [T,B,E]
  float* avg_out  = (float*)d_out + (size_t)Tn * Bn * En;          // [B,T,S]

  char* ws = (char*)d_ws;
  const size_t MB = 1u << 20;
  __bf16* q_ws  = (__bf16*)(ws);                    // [B,H,T,D] bf16, 8 MB
  __bf16* k_ws  = (__bf16*)(ws + 8 * MB);           // 8 MB
  __bf16* v_ws  = (__bf16*)(ws + 16 * MB);          // 8 MB
  __bf16* vt_ws = (__bf16*)(ws + 24 * MB);          // 8 MB (aliases xq_bf)
  __bf16* ctx   = (__bf16*)(ws + 32 * MB);          // 8 MB (aliases xk_bf)
  float*  adj_g = (float*)(ws + 40 * MB);           // [B*H][T] 256 KB
  __bf16* xq_bf = vt_ws;                            // dead before transpose
  __bf16* xk_bf = ctx;                              // dead before flash
  __bf16* xv_bf = (__bf16*)(ws + 40 * MB + 512 * 1024);   // 8 MB
  __bf16* w3_bf = (__bf16*)(ws + 48 * MB + 512 * 1024);   // 6 MB
  __bf16* wo_bf = (__bf16*)(ws + 54 * MB + 512 * 1024);   // 2 MB

  k_cvt<<<8192, 256, 0, stream>>>(query, key, value, in_w, out_w,
                                  xq_bf, xk_bf, xv_bf, w3_bf, wo_bf);
  k_qkv<<<dim3(32, 24), 256, 0, stream>>>(xq_bf, xk_bf, xv_bf, w3_bf, in_b,
                                          q_ws, k_ws, v_ws);
  k_transpose_v<<<1024, 256, 0, stream>>>(v_ws, vt_ws);
  k_flash<<<512, 256, 0, stream>>>(q_ws, k_ws, vt_ws, ctx, adj_g);
  k_avgw<<<2048, 256, 0, stream>>>(q_ws, k_ws, adj_g, avg_out);
  k_outproj<<<dim3(32, 8), 256, 0, stream>>>(ctx, wo_bf, out_b, attn_out);
}